// Round 1
// baseline (370.525 us; speedup 1.0000x reference)
//
#include <hip/hip_runtime.h>

#define NUM_CLASSES 21
// ws layout: [0..20]=t_cnt, [21..41]=p_cnt, [42..62]=inter
#define WS_INTS (3 * NUM_CLASSES)

__global__ void zero_ws_kernel(unsigned int* ws) {
    int i = threadIdx.x;
    if (i < WS_INTS) ws[i] = 0u;
}

// Each thread processes 4 consecutive pixels = 84 floats = 336 bytes (16B aligned).
__global__ __launch_bounds__(256) void hist_kernel(const float* __restrict__ yt,
                                                   const float* __restrict__ yp,
                                                   unsigned int* __restrict__ ws,
                                                   long long npix_groups,
                                                   long long npix) {
    __shared__ unsigned int h[WS_INTS];
    for (int i = threadIdx.x; i < WS_INTS; i += blockDim.x) h[i] = 0u;
    __syncthreads();

    long long gid = (long long)blockIdx.x * blockDim.x + threadIdx.x;

    if (gid < npix_groups) {
        const float4* t4 = (const float4*)yt + gid * NUM_CLASSES;  // 21 float4 = 4 pixels
        const float4* p4 = (const float4*)yp + gid * NUM_CLASSES;

        float tbest[4];
        int   tidx[4];
#pragma unroll
        for (int p = 0; p < 4; ++p) { tbest[p] = -__builtin_inff(); tidx[p] = 0; }
#pragma unroll
        for (int q = 0; q < NUM_CLASSES; ++q) {
            float4 v = t4[q];
            float vals[4] = {v.x, v.y, v.z, v.w};
#pragma unroll
            for (int e = 0; e < 4; ++e) {
                int f = 4 * q + e;            // compile-time after unroll
                int p = f / NUM_CLASSES;
                int c = f % NUM_CLASSES;
                if (vals[e] > tbest[p]) { tbest[p] = vals[e]; tidx[p] = c; }
            }
        }

        float pbest[4];
        int   pidx[4];
#pragma unroll
        for (int p = 0; p < 4; ++p) { pbest[p] = -__builtin_inff(); pidx[p] = 0; }
#pragma unroll
        for (int q = 0; q < NUM_CLASSES; ++q) {
            float4 v = p4[q];
            float vals[4] = {v.x, v.y, v.z, v.w};
#pragma unroll
            for (int e = 0; e < 4; ++e) {
                int f = 4 * q + e;
                int p = f / NUM_CLASSES;
                int c = f % NUM_CLASSES;
                if (vals[e] > pbest[p]) { pbest[p] = vals[e]; pidx[p] = c; }
            }
        }

#pragma unroll
        for (int p = 0; p < 4; ++p) {
            atomicAdd(&h[tidx[p]], 1u);
            atomicAdd(&h[NUM_CLASSES + pidx[p]], 1u);
            if (tidx[p] == pidx[p]) atomicAdd(&h[2 * NUM_CLASSES + tidx[p]], 1u);
        }
    } else if (gid == npix_groups) {
        // scalar tail (npix not divisible by 4) — not taken for 8*512*512 but kept for safety
        for (long long pix = npix_groups * 4; pix < npix; ++pix) {
            const float* t = yt + pix * NUM_CLASSES;
            const float* p = yp + pix * NUM_CLASSES;
            float tb = t[0], pb = p[0];
            int ti = 0, pi = 0;
            for (int c = 1; c < NUM_CLASSES; ++c) {
                if (t[c] > tb) { tb = t[c]; ti = c; }
                if (p[c] > pb) { pb = p[c]; pi = c; }
            }
            atomicAdd(&h[ti], 1u);
            atomicAdd(&h[NUM_CLASSES + pi], 1u);
            if (ti == pi) atomicAdd(&h[2 * NUM_CLASSES + ti], 1u);
        }
    }

    __syncthreads();
    for (int i = threadIdx.x; i < WS_INTS; i += blockDim.x) {
        if (h[i]) atomicAdd(&ws[i], h[i]);
    }
}

__global__ void finalize_kernel(const unsigned int* __restrict__ ws,
                                float* __restrict__ out) {
    int c = threadIdx.x;  // 64 threads, one wave
    float iou = 0.0f, valid = 0.0f;
    if (c < NUM_CLASSES) {
        float inter = (float)ws[2 * NUM_CLASSES + c];
        float uni   = (float)ws[c] + (float)ws[NUM_CLASSES + c] - inter;
        if (uni > 0.0f) { iou = inter / uni; valid = 1.0f; }
    }
#pragma unroll
    for (int off = 32; off > 0; off >>= 1) {
        iou   += __shfl_down(iou, off);
        valid += __shfl_down(valid, off);
    }
    if (c == 0) out[0] = iou / valid;
}

extern "C" void kernel_launch(void* const* d_in, const int* in_sizes, int n_in,
                              void* d_out, int out_size, void* d_ws, size_t ws_size,
                              hipStream_t stream) {
    const float* y_true = (const float*)d_in[0];
    const float* y_pred = (const float*)d_in[1];
    float* out = (float*)d_out;
    unsigned int* ws = (unsigned int*)d_ws;

    long long total = (long long)in_sizes[0];            // 44,040,192
    long long npix = total / NUM_CLASSES;                // 2,097,152
    long long npix_groups = npix / 4;                    // 524,288
    long long tail = npix - npix_groups * 4;

    long long nthreads = npix_groups + (tail ? 1 : 0);
    int block = 256;
    long long grid = (nthreads + block - 1) / block;     // 2048

    zero_ws_kernel<<<1, 64, 0, stream>>>(ws);
    hist_kernel<<<(int)grid, block, 0, stream>>>(y_true, y_pred, ws, npix_groups, npix);
    finalize_kernel<<<1, 64, 0, stream>>>(ws, out);
}

// Round 2
// 351.382 us; speedup vs baseline: 1.0545x; 1.0545x over previous
//
#include <hip/hip_runtime.h>
#include <stdint.h>

#define NUM_CLASSES 21
// ws layout: [0..20]=t_cnt, [21..41]=p_cnt, [42..62]=inter
#define WS_INTS (3 * NUM_CLASSES)
#define TILE_PIX 256
#define TILE_WORDS (TILE_PIX * NUM_CLASSES)   // 5376 words = 21504 B = 21 x 1KB
#define STAGE_INSTR 21                        // 1KB wave-instructions per array per tile

typedef __attribute__((address_space(3))) uint32_t lds_u32;
typedef __attribute__((address_space(1))) const uint32_t glb_u32;

__global__ void zero_ws_kernel(unsigned int* ws) {
    int i = threadIdx.x;
    if (i < WS_INTS) ws[i] = 0u;
}

__global__ __launch_bounds__(256) void hist_kernel(const float* __restrict__ yt,
                                                   const float* __restrict__ yp,
                                                   unsigned int* __restrict__ ws,
                                                   long long npix) {
    __shared__ uint32_t ldsT[TILE_WORDS];
    __shared__ uint32_t ldsP[TILE_WORDS];
    __shared__ unsigned int h[WS_INTS];

    for (int i = threadIdx.x; i < WS_INTS; i += 256) h[i] = 0u;
    __syncthreads();

    const long long ntiles = (npix + TILE_PIX - 1) / TILE_PIX;
    const int wave = threadIdx.x >> 6;
    const int lane = threadIdx.x & 63;

    for (long long tile = blockIdx.x; tile < ntiles; tile += gridDim.x) {
        const long long pix0 = tile * TILE_PIX;
        const bool full = (pix0 + TILE_PIX) <= npix;   // block-uniform

        if (full) {
            // ---- stage: coalesced 1KB global->LDS async copies, no VGPR round-trip
            const uint32_t* gt = (const uint32_t*)yt + pix0 * NUM_CLASSES;
            const uint32_t* gp = (const uint32_t*)yp + pix0 * NUM_CLASSES;
#pragma unroll
            for (int i = wave; i < STAGE_INSTR; i += 4) {
                __builtin_amdgcn_global_load_lds((glb_u32*)(gt + i * 256 + lane * 4),
                                                 (lds_u32*)&ldsT[i * 256], 16, 0, 0);
                __builtin_amdgcn_global_load_lds((glb_u32*)(gp + i * 256 + lane * 4),
                                                 (lds_u32*)&ldsP[i * 256], 16, 0, 0);
            }
            __syncthreads();   // drains vmcnt + makes staged data visible

            // ---- compute: each thread argmaxes its own pixel from LDS
            // word index tid*21+c: for fixed c, 64 lanes cover each bank exactly 2x (free)
            const float* tp = (const float*)&ldsT[(unsigned)threadIdx.x * NUM_CLASSES];
            const float* pp = (const float*)&ldsP[(unsigned)threadIdx.x * NUM_CLASSES];
            float tb = tp[0]; int ti = 0;
            float pb = pp[0]; int pi = 0;
#pragma unroll
            for (int c = 1; c < NUM_CLASSES; ++c) {
                float tv = tp[c], pv = pp[c];
                if (tv > tb) { tb = tv; ti = c; }   // strict > == argmax-first semantics
                if (pv > pb) { pb = pv; pi = c; }
            }
            atomicAdd(&h[ti], 1u);
            atomicAdd(&h[NUM_CLASSES + pi], 1u);
            if (ti == pi) atomicAdd(&h[2 * NUM_CLASSES + ti], 1u);
            __syncthreads();   // protect LDS from next tile's staging
        } else {
            // ---- partial tail tile: direct (uncoalesced) global path, guarded
            long long pix = pix0 + threadIdx.x;
            if (pix < npix) {
                const float* t = yt + pix * NUM_CLASSES;
                const float* p = yp + pix * NUM_CLASSES;
                float tb = t[0], pb = p[0];
                int ti = 0, pi = 0;
                for (int c = 1; c < NUM_CLASSES; ++c) {
                    if (t[c] > tb) { tb = t[c]; ti = c; }
                    if (p[c] > pb) { pb = p[c]; pi = c; }
                }
                atomicAdd(&h[ti], 1u);
                atomicAdd(&h[NUM_CLASSES + pi], 1u);
                if (ti == pi) atomicAdd(&h[2 * NUM_CLASSES + ti], 1u);
            }
        }
    }

    __syncthreads();
    for (int i = threadIdx.x; i < WS_INTS; i += 256) {
        if (h[i]) atomicAdd(&ws[i], h[i]);
    }
}

__global__ void finalize_kernel(const unsigned int* __restrict__ ws,
                                float* __restrict__ out) {
    int c = threadIdx.x;  // one wave
    float iou = 0.0f, valid = 0.0f;
    if (c < NUM_CLASSES) {
        float inter = (float)ws[2 * NUM_CLASSES + c];
        float uni   = (float)ws[c] + (float)ws[NUM_CLASSES + c] - inter;
        if (uni > 0.0f) { iou = inter / uni; valid = 1.0f; }
    }
#pragma unroll
    for (int off = 32; off > 0; off >>= 1) {
        iou   += __shfl_down(iou, off);
        valid += __shfl_down(valid, off);
    }
    if (c == 0) out[0] = iou / valid;
}

extern "C" void kernel_launch(void* const* d_in, const int* in_sizes, int n_in,
                              void* d_out, int out_size, void* d_ws, size_t ws_size,
                              hipStream_t stream) {
    const float* y_true = (const float*)d_in[0];
    const float* y_pred = (const float*)d_in[1];
    float* out = (float*)d_out;
    unsigned int* ws = (unsigned int*)d_ws;

    long long total = (long long)in_sizes[0];   // 44,040,192
    long long npix = total / NUM_CLASSES;       // 2,097,152

    int block = 256;
    int grid = 2048;                            // 8 blocks/CU queued; 3 resident (LDS-bound)

    zero_ws_kernel<<<1, 64, 0, stream>>>(ws);
    hist_kernel<<<grid, block, 0, stream>>>(y_true, y_pred, ws, npix);
    finalize_kernel<<<1, 64, 0, stream>>>(ws, out);
}

// Round 3
// 351.050 us; speedup vs baseline: 1.0555x; 1.0009x over previous
//
#include <hip/hip_runtime.h>
#include <stdint.h>

#define NUM_CLASSES 21
// ws layout: [0..20]=t_cnt, [21..41]=p_cnt, [42..62]=inter
#define WS_INTS (3 * NUM_CLASSES)

// Wave-private tile: 64 pixels x 21 floats = 1344 words = 5376 B per array.
#define TILE_PIX 64
#define WAVE_WORDS_PER_ARR (TILE_PIX * NUM_CLASSES)      // 1344
#define WAVE_WORDS (2 * WAVE_WORDS_PER_ARR)              // 2688 (T then P)
#define WAVES_PER_BLOCK 4

typedef __attribute__((address_space(3))) uint32_t lds_u32;
typedef __attribute__((address_space(1))) const uint32_t glb_u32;

__global__ void zero_ws_kernel(unsigned int* ws) {
    int i = threadIdx.x;
    if (i < WS_INTS) ws[i] = 0u;
}

__device__ __forceinline__ void stage_wave_tile(const uint32_t* __restrict__ g,
                                                uint32_t* ldsbase, int lane) {
    // 5376 B = 5 x 1KB (dwordx4) + 1 x 256B (dword); contiguous, fully coalesced
#pragma unroll
    for (int i = 0; i < 5; ++i) {
        __builtin_amdgcn_global_load_lds((glb_u32*)(g + i * 256 + lane * 4),
                                         (lds_u32*)(ldsbase + i * 256), 16, 0, 0);
    }
    __builtin_amdgcn_global_load_lds((glb_u32*)(g + 1280 + lane),
                                     (lds_u32*)(ldsbase + 1280), 4, 0, 0);
}

__global__ __launch_bounds__(256) void hist_kernel(const float* __restrict__ yt,
                                                   const float* __restrict__ yp,
                                                   unsigned int* __restrict__ ws,
                                                   long long npix) {
    __shared__ uint32_t lds[WAVES_PER_BLOCK * WAVE_WORDS];   // 43008 B
    __shared__ unsigned int h[WS_INTS];

    for (int i = threadIdx.x; i < WS_INTS; i += 256) h[i] = 0u;
    __syncthreads();

    const int wave = threadIdx.x >> 6;
    const int lane = threadIdx.x & 63;
    uint32_t* myT = lds + wave * WAVE_WORDS;
    uint32_t* myP = myT + WAVE_WORDS_PER_ARR;

    const long long ntiles = (npix + TILE_PIX - 1) / TILE_PIX;
    const long long wave_slots = (long long)gridDim.x * WAVES_PER_BLOCK;

    for (long long tile = (long long)blockIdx.x * WAVES_PER_BLOCK + wave;
         tile < ntiles; tile += wave_slots) {
        const long long pix0 = tile * TILE_PIX;

        if (pix0 + TILE_PIX <= npix) {
            // ensure previous iteration's LDS reads retired before DMA overwrites
            asm volatile("s_waitcnt lgkmcnt(0)" ::: "memory");
            stage_wave_tile((const uint32_t*)yt + pix0 * NUM_CLASSES, myT, lane);
            stage_wave_tile((const uint32_t*)yp + pix0 * NUM_CLASSES, myP, lane);
            // wave-local wait: only THIS wave's DMA queue drains; no block barrier
            asm volatile("s_waitcnt vmcnt(0)" ::: "memory");

            // lane's pixel: word index lane*21+c -> 2-way bank aliasing (free)
            const float* tp = (const float*)(myT + lane * NUM_CLASSES);
            const float* pp = (const float*)(myP + lane * NUM_CLASSES);
            float tb = tp[0]; int ti = 0;
            float pb = pp[0]; int pi = 0;
#pragma unroll
            for (int c = 1; c < NUM_CLASSES; ++c) {
                float tv = tp[c], pv = pp[c];
                if (tv > tb) { tb = tv; ti = c; }   // strict > == argmax-first semantics
                if (pv > pb) { pb = pv; pi = c; }
            }
            atomicAdd(&h[ti], 1u);
            atomicAdd(&h[NUM_CLASSES + pi], 1u);
            if (ti == pi) atomicAdd(&h[2 * NUM_CLASSES + ti], 1u);
        } else {
            // partial tail tile (not taken for 8*512*512): direct global path
            long long pix = pix0 + lane;
            if (pix < npix) {
                const float* t = yt + pix * NUM_CLASSES;
                const float* p = yp + pix * NUM_CLASSES;
                float tb = t[0], pb = p[0];
                int ti = 0, pi = 0;
                for (int c = 1; c < NUM_CLASSES; ++c) {
                    if (t[c] > tb) { tb = t[c]; ti = c; }
                    if (p[c] > pb) { pb = p[c]; pi = c; }
                }
                atomicAdd(&h[ti], 1u);
                atomicAdd(&h[NUM_CLASSES + pi], 1u);
                if (ti == pi) atomicAdd(&h[2 * NUM_CLASSES + ti], 1u);
            }
        }
    }

    __syncthreads();
    for (int i = threadIdx.x; i < WS_INTS; i += 256) {
        if (h[i]) atomicAdd(&ws[i], h[i]);
    }
}

__global__ void finalize_kernel(const unsigned int* __restrict__ ws,
                                float* __restrict__ out) {
    int c = threadIdx.x;  // one wave
    float iou = 0.0f, valid = 0.0f;
    if (c < NUM_CLASSES) {
        float inter = (float)ws[2 * NUM_CLASSES + c];
        float uni   = (float)ws[c] + (float)ws[NUM_CLASSES + c] - inter;
        if (uni > 0.0f) { iou = inter / uni; valid = 1.0f; }
    }
#pragma unroll
    for (int off = 32; off > 0; off >>= 1) {
        iou   += __shfl_down(iou, off);
        valid += __shfl_down(valid, off);
    }
    if (c == 0) out[0] = iou / valid;
}

extern "C" void kernel_launch(void* const* d_in, const int* in_sizes, int n_in,
                              void* d_out, int out_size, void* d_ws, size_t ws_size,
                              hipStream_t stream) {
    const float* y_true = (const float*)d_in[0];
    const float* y_pred = (const float*)d_in[1];
    float* out = (float*)d_out;
    unsigned int* ws = (unsigned int*)d_ws;

    long long total = (long long)in_sizes[0];   // 44,040,192
    long long npix = total / NUM_CLASSES;       // 2,097,152

    int block = 256;                            // 4 waves, each with a private 10.5KB tile
    int grid = 2048;                            // 32768 tiles / 8192 wave-slots = 4 iters/wave

    zero_ws_kernel<<<1, 64, 0, stream>>>(ws);
    hist_kernel<<<grid, block, 0, stream>>>(y_true, y_pred, ws, npix);
    finalize_kernel<<<1, 64, 0, stream>>>(ws, out);
}

// Round 4
// 343.307 us; speedup vs baseline: 1.0793x; 1.0226x over previous
//
#include <hip/hip_runtime.h>
#include <stdint.h>

#define NUM_CLASSES 21
// ws layout: [0..20]=t_cnt, [21..41]=p_cnt, [42..62]=inter
#define WS_INTS (3 * NUM_CLASSES)

__global__ void zero_ws_kernel(unsigned int* ws) {
    int i = threadIdx.x;
    if (i < WS_INTS) ws[i] = 0u;
}

// Argmax of 4 consecutive pixels packed in 21 float4 registers.
// Serial strict-> scan == jnp.argmax first-max tie semantics.
__device__ __forceinline__ void argmax4(const float4* __restrict__ v, int* __restrict__ out_idx) {
    float best[4];
    int   idx[4];
#pragma unroll
    for (int p = 0; p < 4; ++p) { best[p] = -__builtin_inff(); idx[p] = 0; }
#pragma unroll
    for (int q = 0; q < NUM_CLASSES; ++q) {
        float vals[4] = {v[q].x, v[q].y, v[q].z, v[q].w};
#pragma unroll
        for (int e = 0; e < 4; ++e) {
            int f = 4 * q + e;           // compile-time after unroll
            int p = f / NUM_CLASSES;
            int c = f % NUM_CLASSES;
            if (vals[e] > best[p]) { best[p] = vals[e]; idx[p] = c; }
        }
    }
#pragma unroll
    for (int p = 0; p < 4; ++p) out_idx[p] = idx[p];
}

__global__ __launch_bounds__(256, 4) void hist_kernel(const float* __restrict__ yt,
                                                      const float* __restrict__ yp,
                                                      unsigned int* __restrict__ ws,
                                                      long long npix) {
    __shared__ unsigned int h[WS_INTS];
    for (int i = threadIdx.x; i < WS_INTS; i += 256) h[i] = 0u;
    __syncthreads();

    const long long ngroups = npix >> 2;                 // 4-pixel groups
    const long long tail = npix - ngroups * 4;
    const long long nthreads_needed = ngroups + (tail ? 1 : 0);
    const long long stride = (long long)gridDim.x * 256;

    for (long long g = (long long)blockIdx.x * 256 + threadIdx.x;
         g < nthreads_needed; g += stride) {
        if (g < ngroups) {
            const float4* t4 = (const float4*)yt + g * NUM_CLASSES;  // 21 float4 = 4 pixels
            const float4* p4 = (const float4*)yp + g * NUM_CLASSES;

            // ---- T phase: issue ALL 21 loads before any compare (deep vmcnt queue)
            float4 vt[NUM_CLASSES];
#pragma unroll
            for (int q = 0; q < NUM_CLASSES; ++q) vt[q] = t4[q];
            __builtin_amdgcn_sched_barrier(0);
            int ti[4];
            argmax4(vt, ti);

            // ---- P phase
            float4 vp[NUM_CLASSES];
#pragma unroll
            for (int q = 0; q < NUM_CLASSES; ++q) vp[q] = p4[q];
            __builtin_amdgcn_sched_barrier(0);
            int pi[4];
            argmax4(vp, pi);

#pragma unroll
            for (int p = 0; p < 4; ++p) {
                atomicAdd(&h[ti[p]], 1u);
                atomicAdd(&h[NUM_CLASSES + pi[p]], 1u);
                if (ti[p] == pi[p]) atomicAdd(&h[2 * NUM_CLASSES + ti[p]], 1u);
            }
        } else {
            // scalar tail (npix % 4 != 0) — not taken for 8*512*512
            for (long long pix = ngroups * 4; pix < npix; ++pix) {
                const float* t = yt + pix * NUM_CLASSES;
                const float* p = yp + pix * NUM_CLASSES;
                float tb = t[0], pb = p[0];
                int tii = 0, pii = 0;
                for (int c = 1; c < NUM_CLASSES; ++c) {
                    if (t[c] > tb) { tb = t[c]; tii = c; }
                    if (p[c] > pb) { pb = p[c]; pii = c; }
                }
                atomicAdd(&h[tii], 1u);
                atomicAdd(&h[NUM_CLASSES + pii], 1u);
                if (tii == pii) atomicAdd(&h[2 * NUM_CLASSES + tii], 1u);
            }
        }
    }

    __syncthreads();
    for (int i = threadIdx.x; i < WS_INTS; i += 256) {
        if (h[i]) atomicAdd(&ws[i], h[i]);
    }
}

__global__ void finalize_kernel(const unsigned int* __restrict__ ws,
                                float* __restrict__ out) {
    int c = threadIdx.x;  // one wave
    float iou = 0.0f, valid = 0.0f;
    if (c < NUM_CLASSES) {
        float inter = (float)ws[2 * NUM_CLASSES + c];
        float uni   = (float)ws[c] + (float)ws[NUM_CLASSES + c] - inter;
        if (uni > 0.0f) { iou = inter / uni; valid = 1.0f; }
    }
#pragma unroll
    for (int off = 32; off > 0; off >>= 1) {
        iou   += __shfl_down(iou, off);
        valid += __shfl_down(valid, off);
    }
    if (c == 0) out[0] = iou / valid;
}

extern "C" void kernel_launch(void* const* d_in, const int* in_sizes, int n_in,
                              void* d_out, int out_size, void* d_ws, size_t ws_size,
                              hipStream_t stream) {
    const float* y_true = (const float*)d_in[0];
    const float* y_pred = (const float*)d_in[1];
    float* out = (float*)d_out;
    unsigned int* ws = (unsigned int*)d_ws;

    long long total = (long long)in_sizes[0];   // 44,040,192
    long long npix = total / NUM_CLASSES;       // 2,097,152

    int block = 256;
    int grid = 1024;   // 4 blocks/CU co-resident at <=128 VGPR; 2 grid-stride iters/thread

    zero_ws_kernel<<<1, 64, 0, stream>>>(ws);
    hist_kernel<<<grid, block, 0, stream>>>(y_true, y_pred, ws, npix);
    finalize_kernel<<<1, 64, 0, stream>>>(ws, out);
}